// Round 5
// baseline (117.644 us; speedup 1.0000x reference)
//
#include <hip/hip_runtime.h>

#define R_RAYS 16384
#define S_VALS 64
#define NSAMP 128
#define Z_ALL 192
#define WEPS 1e-5f

typedef float f32x4 __attribute__((ext_vector_type(4)));

__device__ __forceinline__ float uval(int j) {
    return (j == 127) ? 1.0f : (float)j * (1.0f / 127.0f);
}

__global__ __launch_bounds__(256, 8) void ray_sampler_kernel(
    const float* __restrict__ rays_d,
    const float* __restrict__ rays_o,
    const float* __restrict__ z_vals,
    const float* __restrict__ weights,
    float* __restrict__ pts_out,
    float* __restrict__ zall_out)
{
    __shared__ __align__(16) float s_za[4][Z_ALL];   // merged z per ray (only LDS)

    const int wid  = threadIdx.x >> 6;
    const int lane = threadIdx.x & 63;
    const int ray  = blockIdx.x * 4 + wid;       // ray = b*R + r
    const int r    = ray & (R_RAYS - 1);

    // hoist independent global loads
    float ox = rays_o[ray * 3 + 0], oy = rays_o[ray * 3 + 1], oz = rays_o[ray * 3 + 2];
    float dx = rays_d[ray * 3 + 0], dy = rays_d[ray * 3 + 1], dz = rays_d[ray * 3 + 2];

    // ---- per-lane register state: zv_l, zv_{l+1}, zh_l, zh_{l+1} ----
    float zv  = z_vals[r * S_VALS + lane];
    float zv1 = __shfl_down(zv, 1);
    float zv2 = __shfl_down(zv, 2);
    float zh  = 0.5f * (zv + zv1);        // bins[l]   (valid l<=62)
    float zh1 = 0.5f * (zv1 + zv2);       // bins[l+1] (valid l<=61)

    // ---- weights scan -> cdf interval [clo, chi) per lane ----
    float w = 0.0f;
    if (lane < 62) w = weights[(size_t)ray * S_VALS + lane + 1] + WEPS;
    float sc = w;
    #pragma unroll
    for (int off = 1; off < 64; off <<= 1) {
        float y = __shfl_up(sc, off);
        if (lane >= off) sc += y;
    }
    float total = __shfl(sc, 61);
    float scp   = __shfl_up(sc, 1);
    float clo = (lane == 0) ? 0.0f : scp / total;   // cdf[l]
    float chi = sc / total;                          // cdf[l+1] (lane62: ==clo)
    float denom = chi - clo;
    float rden  = (denom < 1e-5f) ? 1.0f : 1.0f / denom;
    float bhi = (lane >= 62) ? zh : zh1;

    // ---- ownership: js = min j with u_j >= clo (exact partition via shfl) ----
    int js = (int)ceilf(clo * 127.0f);
    js = js < 0 ? 0 : (js > 128 ? 128 : js);
    while (js > 0 && uval(js - 1) >= clo) --js;
    while (js < 128 && uval(js) < clo) ++js;
    int jn = __shfl_down(js, 1);
    int je = (lane == 62) ? 128 : ((lane > 62) ? js : jn);

    // ---- emit owned samples directly at final merged rank ----
    // sample rank = j + (l+1) + (zv_{l+1} <= s); bijective with zv ranks below
    int cnt_lt = 0;
    for (int j = js; j < je; ++j) {
        float u = uval(j);
        float t = (u - clo) * rden;
        float s = fmaf(t, bhi - zh, zh);
        int ind = (zv1 <= s) ? 1 : 0;
        cnt_lt += 1 - ind;
        s_za[wid][j + lane + 1 + ind] = s;
    }
    // zv ranks: rank_z(l+1) = (l+1) + js + #(own samples < zv_{l+1}); rank_z(0)=0
    if (lane == 0) s_za[wid][0] = zv;
    if (lane <= 62) s_za[wid][lane + 1 + js + cnt_lt] = zv1;

    // ---- per-wave vectorized drain (no barrier; wave-private LDS slice) ----
    // per ray: pts 144 float4 + z_all 48 float4 = 192 float4 = 3 per lane
    const float* za = s_za[wid];
    const size_t pbase = (size_t)ray * (Z_ALL * 3);
    const size_t zbase = (size_t)ray * Z_ALL;
    #pragma unroll
    for (int t = 0; t < 3; ++t) {
        int idx = lane + 64 * t;                  // 0..191
        if (idx < 144) {
            int f0 = idx * 4;                     // 0..572
            int s0 = f0 / 3;
            float z0 = za[s0];
            float z1 = za[s0 + 1];
            f32x4 v;
            #pragma unroll
            for (int i = 0; i < 4; ++i) {
                int gi = f0 + i;
                int s  = gi / 3;
                int c  = gi - s * 3;
                float z = (s == s0) ? z0 : z1;
                float o = (c == 0) ? ox : ((c == 1) ? oy : oz);
                float d = (c == 0) ? dx : ((c == 1) ? dy : dz);
                v[i] = fmaf(d, z, o);
            }
            *(f32x4*)(pts_out + pbase + f0) = v;
        } else {
            int j = idx - 144;                    // 0..47
            f32x4 v = *(const f32x4*)&za[j * 4];
            *(f32x4*)(zall_out + zbase + j * 4) = v;
        }
    }
}

extern "C" void kernel_launch(void* const* d_in, const int* in_sizes, int n_in,
                              void* d_out, int out_size, void* d_ws, size_t ws_size,
                              hipStream_t stream) {
    const float* rays_d  = (const float*)d_in[0];
    const float* rays_o  = (const float*)d_in[1];
    const float* z_vals  = (const float*)d_in[2];
    const float* weights = (const float*)d_in[3];

    float* pts  = (float*)d_out;                       // (8,16384,192,3)
    float* zall = pts + (size_t)8 * 16384 * 192 * 3;   // (8,16384,192)

    const int total_rays = 8 * 16384;                  // 131072
    dim3 grid(total_rays / 4), block(256);
    ray_sampler_kernel<<<grid, block, 0, stream>>>(rays_d, rays_o, z_vals,
                                                   weights, pts, zall);
}

// Round 6
// 99.701 us; speedup vs baseline: 1.1800x; 1.1800x over previous
//
#include <hip/hip_runtime.h>

#define R_RAYS 16384
#define S_VALS 64
#define NSAMP 128
#define Z_ALL 192
#define WEPS 1e-5f

typedef float f32x4 __attribute__((ext_vector_type(4)));

__device__ __forceinline__ float uval(int j) {
    return (j == 127) ? 1.0f : (float)j * (1.0f / 127.0f);
}

__global__ __launch_bounds__(256, 8) void ray_sampler_kernel(
    const float* __restrict__ rays_d,
    const float* __restrict__ rays_o,
    const float* __restrict__ z_vals,
    const float* __restrict__ weights,
    float* __restrict__ pts_out,
    float* __restrict__ zall_out)
{
    __shared__ __align__(16) float s_za[4][Z_ALL];   // merged z per ray (only LDS)

    const int wid  = threadIdx.x >> 6;
    const int lane = threadIdx.x & 63;
    const int ray  = blockIdx.x * 4 + wid;       // ray = b*R + r
    const int r    = ray & (R_RAYS - 1);

    // hoist independent global loads
    float ox = rays_o[ray * 3 + 0], oy = rays_o[ray * 3 + 1], oz = rays_o[ray * 3 + 2];
    float dx = rays_d[ray * 3 + 0], dy = rays_d[ray * 3 + 1], dz = rays_d[ray * 3 + 2];

    // ---- per-lane register state: zv_l, zv_{l+1}, zh_l, zh_{l+1} ----
    float zv  = z_vals[r * S_VALS + lane];
    float zv1 = __shfl_down(zv, 1);
    float zv2 = __shfl_down(zv, 2);
    float zh  = 0.5f * (zv + zv1);        // bins[l]   (valid l<=62)
    float zh1 = 0.5f * (zv1 + zv2);       // bins[l+1] (valid l<=61)

    // ---- weights scan -> cdf interval [clo, chi) per lane ----
    float w = 0.0f;
    if (lane < 62) w = weights[(size_t)ray * S_VALS + lane + 1] + WEPS;
    float sc = w;
    #pragma unroll
    for (int off = 1; off < 64; off <<= 1) {
        float y = __shfl_up(sc, off);
        if (lane >= off) sc += y;
    }
    float total = __shfl(sc, 61);
    float scp   = __shfl_up(sc, 1);
    float clo = (lane == 0) ? 0.0f : scp / total;   // cdf[l]
    float chi = sc / total;                          // cdf[l+1] (lane62: ==clo)
    float denom = chi - clo;
    float rden  = (denom < 1e-5f) ? 1.0f : 1.0f / denom;
    float bhi = (lane >= 62) ? zh : zh1;

    // ---- ownership: js = min j with u_j >= clo (exact partition via shfl) ----
    int js = (int)ceilf(clo * 127.0f);
    js = js < 0 ? 0 : (js > 128 ? 128 : js);
    while (js > 0 && uval(js - 1) >= clo) --js;
    while (js < 128 && uval(js) < clo) ++js;
    int jn = __shfl_down(js, 1);
    int je = (lane == 62) ? 128 : ((lane > 62) ? js : jn);

    // ---- emit owned samples directly at final merged rank ----
    // sample rank = j + (l+1) + (zv_{l+1} <= s); bijective with zv ranks below
    int cnt_lt = 0;
    for (int j = js; j < je; ++j) {
        float u = uval(j);
        float t = (u - clo) * rden;
        float s = fmaf(t, bhi - zh, zh);
        int ind = (zv1 <= s) ? 1 : 0;
        cnt_lt += 1 - ind;
        s_za[wid][j + lane + 1 + ind] = s;
    }
    // zv ranks: rank_z(l+1) = (l+1) + js + #(own samples < zv_{l+1}); rank_z(0)=0
    if (lane == 0) s_za[wid][0] = zv;
    if (lane <= 62) s_za[wid][lane + 1 + js + cnt_lt] = zv1;

    // ---- per-wave vectorized drain (no barrier; wave-private LDS slice) ----
    // per ray: pts 144 float4 + z_all 48 float4 = 192 float4 = 3 per lane
    const float* za = s_za[wid];
    const size_t pbase = (size_t)ray * (Z_ALL * 3);
    const size_t zbase = (size_t)ray * Z_ALL;
    #pragma unroll
    for (int t = 0; t < 3; ++t) {
        int idx = lane + 64 * t;                  // 0..191
        if (idx < 144) {
            int f0 = idx * 4;                     // 0..572
            int s0 = f0 / 3;
            float z0 = za[s0];
            float z1 = za[s0 + 1];
            f32x4 v;
            #pragma unroll
            for (int i = 0; i < 4; ++i) {
                int gi = f0 + i;
                int s  = gi / 3;
                int c  = gi - s * 3;
                float z = (s == s0) ? z0 : z1;
                float o = (c == 0) ? ox : ((c == 1) ? oy : oz);
                float d = (c == 0) ? dx : ((c == 1) ? dy : dz);
                v[i] = fmaf(d, z, o);
            }
            __builtin_nontemporal_store(v, (f32x4*)(pts_out + pbase + f0));
        } else {
            int j = idx - 144;                    // 0..47
            f32x4 v = *(const f32x4*)&za[j * 4];
            __builtin_nontemporal_store(v, (f32x4*)(zall_out + zbase + j * 4));
        }
    }
}

extern "C" void kernel_launch(void* const* d_in, const int* in_sizes, int n_in,
                              void* d_out, int out_size, void* d_ws, size_t ws_size,
                              hipStream_t stream) {
    const float* rays_d  = (const float*)d_in[0];
    const float* rays_o  = (const float*)d_in[1];
    const float* z_vals  = (const float*)d_in[2];
    const float* weights = (const float*)d_in[3];

    float* pts  = (float*)d_out;                       // (8,16384,192,3)
    float* zall = pts + (size_t)8 * 16384 * 192 * 3;   // (8,16384,192)

    const int total_rays = 8 * 16384;                  // 131072
    dim3 grid(total_rays / 4), block(256);
    ray_sampler_kernel<<<grid, block, 0, stream>>>(rays_d, rays_o, z_vals,
                                                   weights, pts, zall);
}